// Round 5
// baseline (289.357 us; speedup 1.0000x reference)
//
#include <hip/hip_runtime.h>
#include <hip/hip_bf16.h>
#include <math.h>

#define DD 2048   // hidden dim
#define EE 16     // experts
#define RR 16     // lora rank
#define QO 2048   // q out dim
#define VO 512    // v out dim
#define KS 4      // k-splits in A kernel
#define KRANGE (DD / KS)   // 512
#define KC 256    // k-chunk staged per barrier
#define MT 32     // slots per A-block tile
#define HS 264    // LDS row stride in bf16 elems (256 + 8 pad -> 2-way max)
#define T2 32     // B-side tokens per tile
#define CGQ 8     // q column groups (256 cols)
#define CGV 2     // v column groups

typedef __attribute__((ext_vector_type(8))) short bf16x8;   // 8 bf16 = 4 VGPR
typedef __attribute__((ext_vector_type(4))) float f32x4;

struct Route { int i0, i1; float w0, w1; };

__device__ inline unsigned short f2bf(float x) {
    __hip_bfloat16 b = __float2bfloat16(x);   // RN
    return *reinterpret_cast<unsigned short*>(&b);
}

// ---------------- K0: abT[e][32][2048] bf16 (rows 0-15 = q ranks, 16-31 = v) --
__global__ __launch_bounds__(256) void prep_ab_kernel(
    const float* __restrict__ qa, const float* __restrict__ va,
    unsigned short* __restrict__ abT)
{
    int e  = blockIdx.x;
    int dq = blockIdx.y;                 // 512-wide d range
    __align__(16) __shared__ unsigned short t_s[32 * 128];  // 8 KB
    int tid = threadIdx.x;
    for (int d0 = dq * 512; d0 < dq * 512 + 512; d0 += 128) {
        __syncthreads();
#pragma unroll
        for (int it = 0; it < 8; ++it) {  // 128 d x 16 r, coalesced fp32 reads
            int idx = tid + it * 256;
            int dd = idx >> 4, r = idx & 15;
            float q = qa[((size_t)e * DD + d0 + dd) * RR + r];
            float v = va[((size_t)e * DD + d0 + dd) * RR + r];
            t_s[r * 128 + dd]        = f2bf(q);
            t_s[(16 + r) * 128 + dd] = f2bf(v);
        }
        __syncthreads();
#pragma unroll
        for (int it = 0; it < 2; ++it) {  // 32 rows x 128 bf16, uint4 stores
            int idx = tid + it * 256;
            int row = idx >> 4, c8 = (idx & 15) * 8;
            uint4 v = *(const uint4*)&t_s[row * 128 + c8];
            *(uint4*)&abT[((size_t)e * 32 + row) * DD + d0 + c8] = v;
        }
    }
}

// ---------------- K1: router — wave per token, no barriers, no LDS ----------
// fp64 logits; writes route[tok] and appends (tok*2+k, w) to per-expert lists.
__global__ __launch_bounds__(256) void router_kernel(
    const float* __restrict__ h, const float* __restrict__ rw,
    Route* __restrict__ route, int* __restrict__ cnt,
    int* __restrict__ elist, float* __restrict__ wlist, int n)
{
    int wave = threadIdx.x >> 6;
    int lane = threadIdx.x & 63;
    int tok  = blockIdx.x * 4 + wave;
    if (tok >= n) return;
    int e = lane >> 2, ds = lane & 3;     // 16 experts x 4 d-slices
    const float* hp = h + (size_t)tok * DD;
    const float* rp = rw + (size_t)e * DD;
    double acc0 = 0.0, acc1 = 0.0;        // 2 chains for ILP
    for (int i = 0; i < 64; ++i) {
        int d0 = i * 16 + ds * 4;
        int d1 = d0 + 1024;
        float4 h0 = *(const float4*)&hp[d0];
        float4 r0 = *(const float4*)&rp[d0];
        float4 h1 = *(const float4*)&hp[d1];
        float4 r1 = *(const float4*)&rp[d1];
        acc0 += (double)h0.x * r0.x + (double)h0.y * r0.y
              + (double)h0.z * r0.z + (double)h0.w * r0.w;
        acc1 += (double)h1.x * r1.x + (double)h1.y * r1.y
              + (double)h1.z * r1.z + (double)h1.w * r1.w;
    }
    double acc = acc0 + acc1;
    acc += __shfl_xor(acc, 1, 64);        // reduce 4 d-slices
    acc += __shfl_xor(acc, 2, 64);
    double lg[EE];
#pragma unroll
    for (int i = 0; i < EE; ++i) lg[i] = __shfl(acc, i * 4, 64);  // all lanes
    int i0 = 0;
    for (int i = 1; i < EE; ++i) if (lg[i] > lg[i0]) i0 = i;      // low idx wins
    int i1 = -1;
    for (int i = 0; i < EE; ++i)
        if (i != i0 && (i1 < 0 || lg[i] > lg[i1])) i1 = i;
    if (lane == 0) {
        double mx = lg[i0], Z = 0.0;
        for (int i = 0; i < EE; ++i) Z += exp(lg[i] - mx);
        double p0 = 1.0 / Z;
        double p1 = exp(lg[i1] - mx) / Z;
        double s  = p0 + p1 + 1e-20;
        float w0 = (float)(2.0 * p0 / s);  // scale = ALPHA/R = 2
        float w1 = (float)(2.0 * p1 / s);
        Route rt; rt.i0 = i0; rt.i1 = i1; rt.w0 = w0; rt.w1 = w1;
        route[tok] = rt;
        int p0i = atomicAdd(&cnt[i0], 1);
        elist[(size_t)i0 * n + p0i] = tok * 2 + 0;
        wlist[(size_t)i0 * n + p0i] = w0;
        int p1i = atomicAdd(&cnt[i1], 1);
        elist[(size_t)i1 * n + p1i] = tok * 2 + 1;
        wlist[(size_t)i1 * n + p1i] = w1;
    }
}

// ---------------- K2: A-side bf16 MFMA over compacted slot lists -------------
// grid (EE, ytiles, KS); block = 4 waves; wave -> (mhalf, nhalf) 16x16 quadrant.
// low[entry][ks*32 + col], col 0-15 = q ranks, 16-31 = v ranks; weight applied.
__global__ __launch_bounds__(256) void a_mfma_kernel(
    const float* __restrict__ h, const unsigned short* __restrict__ abT,
    const int* __restrict__ cnt, const int* __restrict__ elist,
    const float* __restrict__ wlist, float* __restrict__ low, int n)
{
    int e  = blockIdx.x;
    int ks = blockIdx.z;
    int me = cnt[e];

    __align__(16) __shared__ unsigned short hb_s[MT * HS];  // 16.9 KB
    __align__(16) __shared__ unsigned short ab_s[MT * HS];  // 16.9 KB
    __shared__ int   sel_e[MT];
    __shared__ float sel_w[MT];

    int tid  = threadIdx.x;
    int lane = tid & 63, wave = tid >> 6;
    int mhalf = wave >> 1, nhalf = wave & 1;
    int l15 = lane & 15, quad = lane >> 4;

    for (int tile = blockIdx.y; tile * MT < me; tile += gridDim.y) {
        __syncthreads();                   // prev iter readers of sel_* done
        if (tid < MT) {
            int sl = tile * MT + tid;
            int entry = 0; float w = 0.f;
            if (sl < me) {
                entry = elist[(size_t)e * n + sl];
                w     = wlist[(size_t)e * n + sl];
            }
            sel_e[tid] = entry; sel_w[tid] = w;
        }
        __syncthreads();

        f32x4 acc = {0.f, 0.f, 0.f, 0.f};
        for (int c = 0; c < KRANGE / KC; ++c) {     // 2 chunks
            int kbase = ks * KRANGE + c * KC;
            if (c) __syncthreads();                 // prev chunk MFMA reads done
            // stage h rows (gather, fp32->bf16): wave reads one full row/instr
#pragma unroll
            for (int it = 0; it < 8; ++it) {
                int idx = tid + it * 256;
                int row = idx >> 6, c4 = (idx & 63) * 4;
                int tokk = sel_e[row] >> 1;
                float4 v = *(const float4*)&h[(size_t)tokk * DD + kbase + c4];
                ushort4 b;
                b.x = f2bf(v.x); b.y = f2bf(v.y); b.z = f2bf(v.z); b.w = f2bf(v.w);
                *(ushort4*)&hb_s[row * HS + c4] = b;
            }
            // stage abT chunk (already bf16): 32 rows x 512 B, coalesced
#pragma unroll
            for (int it = 0; it < 4; ++it) {
                int idx = tid + it * 256;
                int row = idx >> 5, c8 = (idx & 31) * 8;
                uint4 v = *(const uint4*)&abT[((size_t)e * 32 + row) * DD + kbase + c8];
                *(uint4*)&ab_s[row * HS + c8] = v;
            }
            __syncthreads();
#pragma unroll
            for (int s = 0; s < KC / 32; ++s) {     // 8 MFMA steps
                bf16x8 af = *(const bf16x8*)&hb_s[(mhalf * 16 + l15) * HS + s * 32 + quad * 8];
                bf16x8 bf = *(const bf16x8*)&ab_s[(nhalf * 16 + l15) * HS + s * 32 + quad * 8];
                acc = __builtin_amdgcn_mfma_f32_16x16x32_bf16(af, bf, acc, 0, 0, 0);
            }
        }
        // store: D layout col = lane&15, row = quad*4 + reg  [m89/m91 verified]
#pragma unroll
        for (int r = 0; r < 4; ++r) {
            int mrow = quad * 4 + r;
            int sl = tile * MT + mhalf * 16 + mrow;
            if (sl < me) {
                int   entry = sel_e[mhalf * 16 + mrow];
                float w     = sel_w[mhalf * 16 + mrow];
                low[(size_t)entry * (KS * 32) + ks * 32 + nhalf * 16 + l15] = acc[r] * w;
            }
        }
    }
}

// ---------------- K3: B-side, token-major bucketed, no atomics ---------------
__global__ __launch_bounds__(256) void b_kernel(
    const Route* __restrict__ route, const float* __restrict__ low,
    const float* __restrict__ qb, const float* __restrict__ vb,
    float* __restrict__ outq, float* __restrict__ outv, int n)
{
    int t0 = blockIdx.x * T2;
    int cg = blockIdx.y;               // 0..7 -> q cols, 8..9 -> v cols
    int tid = threadIdx.x;

    __shared__ float acc_s[T2 * 256];  // 32 KB
    __shared__ float ls[T2 * 2 * RR];  // 4 KB
    __shared__ int   elist_s[EE * T2]; // 2 KB
    __shared__ int   ecnt[EE];
    __shared__ int   plist[EE];
    __shared__ int   pcnt;
    __shared__ Route rts[T2];

    if (tid < EE) ecnt[tid] = 0;
    if (tid == 0) pcnt = 0;
    if (tid < T2) {
        int tok = t0 + tid;
        Route rt; rt.i0 = -1; rt.i1 = -1; rt.w0 = 0.f; rt.w1 = 0.f;
        if (tok < n) rt = route[tok];
        rts[tid] = rt;
    }
    __syncthreads();
    if (tid < T2 * 2) {
        int j = tid >> 1, k = tid & 1;
        int e = k ? rts[j].i1 : rts[j].i0;
        if (e >= 0) {
            int p = atomicAdd(&ecnt[e], 1);
            elist_s[e * T2 + p] = j * 2 + k;
        }
    }
    int side = (cg >= CGQ) ? 1 : 0;
    {   // stage ls: 64 slots x 4 float4 == 256 tasks == 1/thread; sum KS partials
        int slot = tid >> 2, r4 = (tid & 3) * 4;
        int j = slot >> 1;
        float4 v = make_float4(0.f, 0.f, 0.f, 0.f);
        if (t0 + j < n) {
            const float* lp = low + (size_t)((t0 + j) * 2 + (slot & 1)) * (KS * 32)
                            + side * 16 + r4;
#pragma unroll
            for (int p = 0; p < KS; ++p) {
                float4 q = *(const float4*)(lp + p * 32);
                v.x += q.x; v.y += q.y; v.z += q.z; v.w += q.w;
            }
        }
        *(float4*)&ls[slot * RR + r4] = v;
    }
#pragma unroll
    for (int j = 0; j < T2; ++j) acc_s[j * 256 + tid] = 0.f;
    __syncthreads();
    if (tid < EE && ecnt[tid] > 0) { int p = atomicAdd(&pcnt, 1); plist[p] = tid; }
    __syncthreads();
    int P = pcnt;

    const float* bp; float* outp; int W, colbase;
    if (cg < CGQ) { bp = qb; outp = outq; W = QO; colbase = cg * 256; }
    else          { bp = vb; outp = outv; W = VO; colbase = (cg - CGQ) * 256; }
    int col = colbase + tid;

    if (P > 0) {
        float bc[RR];
        {
            const float* be = bp + (size_t)plist[0] * RR * W + col;
#pragma unroll
            for (int r = 0; r < RR; ++r) bc[r] = be[(size_t)r * W];
        }
        for (int p = 0; p < P; ++p) {
            float bn[RR];
            if (p + 1 < P) {
                const float* be = bp + (size_t)plist[p + 1] * RR * W + col;
#pragma unroll
                for (int r = 0; r < RR; ++r) bn[r] = be[(size_t)r * W];
            }
            int e = plist[p], c = ecnt[e];
            for (int ii = 0; ii < c; ++ii) {
                int sk = elist_s[e * T2 + ii];
                int j  = sk >> 1;
                const float* lp = &ls[sk * RR];
                float4 l0 = *(const float4*)(lp);
                float4 l1 = *(const float4*)(lp + 4);
                float4 l2 = *(const float4*)(lp + 8);
                float4 l3 = *(const float4*)(lp + 12);
                float v = 0.f;
                v = fmaf(l0.x, bc[0],  v); v = fmaf(l0.y, bc[1],  v);
                v = fmaf(l0.z, bc[2],  v); v = fmaf(l0.w, bc[3],  v);
                v = fmaf(l1.x, bc[4],  v); v = fmaf(l1.y, bc[5],  v);
                v = fmaf(l1.z, bc[6],  v); v = fmaf(l1.w, bc[7],  v);
                v = fmaf(l2.x, bc[8],  v); v = fmaf(l2.y, bc[9],  v);
                v = fmaf(l2.z, bc[10], v); v = fmaf(l2.w, bc[11], v);
                v = fmaf(l3.x, bc[12], v); v = fmaf(l3.y, bc[13], v);
                v = fmaf(l3.z, bc[14], v); v = fmaf(l3.w, bc[15], v);
                acc_s[j * 256 + tid] += v;   // thread-private column
            }
            if (p + 1 < P) {
#pragma unroll
                for (int r = 0; r < RR; ++r) bc[r] = bn[r];
            }
        }
    }
    __syncthreads();
    for (int t = tid; t < T2 * 64; t += 256) {  // row-contiguous float4 stores
        int j = t >> 6, fq = (t & 63) * 4;
        int tok = t0 + j;
        if (tok < n) {
            float4 v = *(const float4*)&acc_s[j * 256 + fq];
            *(float4*)&outp[(size_t)tok * W + colbase + fq] = v;
        }
    }
}

extern "C" void kernel_launch(void* const* d_in, const int* in_sizes, int n_in,
                              void* d_out, int out_size, void* d_ws, size_t ws_size,
                              hipStream_t stream) {
    const float* h  = (const float*)d_in[0];
    const float* rw = (const float*)d_in[1];
    const float* qa = (const float*)d_in[2];
    const float* qb = (const float*)d_in[3];
    const float* va = (const float*)d_in[4];
    const float* vb = (const float*)d_in[5];

    int n = in_sizes[0] / DD;
    float* out  = (float*)d_out;
    float* outq = out;
    float* outv = out + (size_t)n * QO;

    // workspace layout (n=4096: ~6.9 MB total; ws proven >= 8.4 MB in R4)
    char* w = (char*)d_ws;
    auto align256 = [](size_t x) { return (x + 255) & ~(size_t)255; };
    Route* route = (Route*)w;                       size_t off = align256((size_t)n * sizeof(Route));
    int*   cnt   = (int*)(w + off);                 off = align256(off + EE * sizeof(int));
    int*   elist = (int*)(w + off);                 off = align256(off + (size_t)EE * n * sizeof(int));
    float* wlist = (float*)(w + off);               off = align256(off + (size_t)EE * n * sizeof(float));
    unsigned short* abT = (unsigned short*)(w + off); off = align256(off + (size_t)EE * 32 * DD * sizeof(unsigned short));
    float* low   = (float*)(w + off);               // n * 2 * KS * 32 * 4 B

    // K0: pack+transpose lora-A weights to bf16 [e][32][2048]
    dim3 g0(EE, 4);
    prep_ab_kernel<<<g0, 256, 0, stream>>>(qa, va, abT);

    // zero per-expert counters (ws is poisoned 0xAA each call)
    hipMemsetAsync(cnt, 0, EE * sizeof(int), stream);

    // K1: router + compaction
    router_kernel<<<(n + 3) / 4, 256, 0, stream>>>(h, rw, route, cnt, elist, wlist, n);

    // K2: MFMA A-side
    int ytiles = (2 * n / EE + MT - 1) / MT + 4;    // avg tiles + skew headroom
    dim3 g2(EE, ytiles, KS);
    a_mfma_kernel<<<g2, 256, 0, stream>>>(h, abT, cnt, elist, wlist, low, n);

    // K3: B-side
    dim3 g3((n + T2 - 1) / T2, CGQ + CGV);
    b_kernel<<<g3, 256, 0, stream>>>(route, low, qb, vb, outq, outv, n);
}

// Round 6
// 272.034 us; speedup vs baseline: 1.0637x; 1.0637x over previous
//
#include <hip/hip_runtime.h>
#include <hip/hip_bf16.h>
#include <math.h>
#include <float.h>

#define DD 2048   // hidden dim
#define EE 16     // experts
#define RR 16     // lora rank
#define QO 2048   // q out dim
#define VO 512    // v out dim
#define KS 4      // k-splits in A kernel
#define KRANGE (DD / KS)   // 512
#define KC 256    // k-chunk staged per barrier
#define MT 32     // slots per A-block tile
#define HS 264    // LDS row stride in bf16 elems (256 + 8 pad -> 2-way max)
#define T2 32     // B-side tokens per tile
#define CGQ 8     // q column groups (256 cols)
#define CGV 2     // v column groups

typedef __attribute__((ext_vector_type(8))) short bf16x8;   // 8 bf16 = 4 VGPR
typedef __attribute__((ext_vector_type(4))) float f32x4;

struct Route { int i0, i1; float w0, w1; };

__device__ inline unsigned short f2bf(float x) {
    __hip_bfloat16 b = __float2bfloat16(x);   // RN
    return *reinterpret_cast<unsigned short*>(&b);
}

// branchless merge of two descending top-2 lists, lower index wins ties
__device__ inline void top2_merge(double& b1, int& b1i, double& b2, int& b2i,
                                  double c1, int c1i, double c2, int c2i) {
    bool cw  = (c1 > b1) || (c1 == b1 && c1i < b1i);
    double n1  = cw ? c1  : b1;
    int    n1i = cw ? c1i : b1i;
    double l   = cw ? b1  : c1;    // loser of top fight
    int    li  = cw ? b1i : c1i;
    double s   = cw ? c2  : b2;    // winner's second
    int    si  = cw ? c2i : b2i;
    bool lw  = (l > s) || (l == s && li < si);
    b1 = n1; b1i = n1i;
    b2 = lw ? l : s; b2i = lw ? li : si;
}

// ---------------- K0: abT[e][32][2048] bf16 (rows 0-15 = q ranks, 16-31 = v) --
__global__ __launch_bounds__(256) void prep_ab_kernel(
    const float* __restrict__ qa, const float* __restrict__ va,
    unsigned short* __restrict__ abT)
{
    int e  = blockIdx.x;
    int dq = blockIdx.y;                 // 512-wide d range
    __align__(16) __shared__ unsigned short t_s[32 * 128];  // 8 KB
    int tid = threadIdx.x;
    for (int d0 = dq * 512; d0 < dq * 512 + 512; d0 += 128) {
        __syncthreads();
#pragma unroll
        for (int it = 0; it < 8; ++it) {  // 128 d x 16 r, coalesced fp32 reads
            int idx = tid + it * 256;
            int dd = idx >> 4, r = idx & 15;
            float q = qa[((size_t)e * DD + d0 + dd) * RR + r];
            float v = va[((size_t)e * DD + d0 + dd) * RR + r];
            t_s[r * 128 + dd]        = f2bf(q);
            t_s[(16 + r) * 128 + dd] = f2bf(v);
        }
        __syncthreads();
#pragma unroll
        for (int it = 0; it < 2; ++it) {  // 32 rows x 128 bf16, uint4 stores
            int idx = tid + it * 256;
            int row = idx >> 4, c8 = (idx & 15) * 8;
            uint4 v = *(const uint4*)&t_s[row * 128 + c8];
            *(uint4*)&abT[((size_t)e * 32 + row) * DD + d0 + c8] = v;
        }
    }
}

// ---------------- K1: router — wave/token, register-only top-2, 1 exp -------
__global__ __launch_bounds__(256) void router_kernel(
    const float* __restrict__ h, const float* __restrict__ rw,
    Route* __restrict__ route, int* __restrict__ cnt,
    int* __restrict__ elist, float* __restrict__ wlist, int n)
{
    int wave = threadIdx.x >> 6;
    int lane = threadIdx.x & 63;
    int tok  = blockIdx.x * 4 + wave;
    if (tok >= n) return;
    int e = lane >> 2, ds = lane & 3;     // 16 experts x 4 d-slices
    const float* hp = h + (size_t)tok * DD;
    const float* rp = rw + (size_t)e * DD;
    double acc0 = 0.0, acc1 = 0.0;        // 2 chains for ILP
    for (int i = 0; i < 64; ++i) {
        int d0 = i * 16 + ds * 4;
        int d1 = d0 + 1024;
        float4 h0 = *(const float4*)&hp[d0];
        float4 r0 = *(const float4*)&rp[d0];
        float4 h1 = *(const float4*)&hp[d1];
        float4 r1 = *(const float4*)&rp[d1];
        acc0 += (double)h0.x * r0.x + (double)h0.y * r0.y
              + (double)h0.z * r0.z + (double)h0.w * r0.w;
        acc1 += (double)h1.x * r1.x + (double)h1.y * r1.y
              + (double)h1.z * r1.z + (double)h1.w * r1.w;
    }
    double acc = acc0 + acc1;
    acc += __shfl_xor(acc, 1, 64);        // reduce 4 d-slices
    acc += __shfl_xor(acc, 2, 64);

    // butterfly top-2 across the 16 expert groups (replica lanes never mix)
    double b1 = acc, b2 = -DBL_MAX;
    int    b1i = e,  b2i = 0x7fffffff;
#pragma unroll
    for (int st = 4; st <= 32; st <<= 1) {
        double c1 = __shfl_xor(b1, st, 64);
        double c2 = __shfl_xor(b2, st, 64);
        int    c1i = __shfl_xor(b1i, st, 64);
        int    c2i = __shfl_xor(b2i, st, 64);
        top2_merge(b1, b1i, b2, b2i, c1, c1i, c2, c2i);
    }
    // w0 = p0/(p0+p1+1e-20); Z cancels, 1e-20 << p0+p1 (>= ~0.12) -> drop
    double r  = exp(b2 - b1);             // <= 1
    float w0 = (float)(2.0 / (1.0 + r));  // scale = ALPHA/R = 2
    float w1 = (float)(2.0 * r / (1.0 + r));
    if (lane == 0) {
        Route rt; rt.i0 = b1i; rt.i1 = b2i; rt.w0 = w0; rt.w1 = w1;
        route[tok] = rt;
        int p0i = atomicAdd(&cnt[b1i], 1);
        elist[(size_t)b1i * n + p0i] = tok * 2 + 0;
        wlist[(size_t)b1i * n + p0i] = w0;
        int p1i = atomicAdd(&cnt[b2i], 1);
        elist[(size_t)b2i * n + p1i] = tok * 2 + 1;
        wlist[(size_t)b2i * n + p1i] = w1;
    }
}

// ---------------- K2: A-side bf16 MFMA over compacted slot lists -------------
// grid (EE, ytiles, KS); block = 4 waves; wave -> (mhalf, nhalf) 16x16 quadrant.
// low[entry][ks*32 + col], col 0-15 = q ranks, 16-31 = v ranks; weight applied.
__global__ __launch_bounds__(256) void a_mfma_kernel(
    const float* __restrict__ h, const unsigned short* __restrict__ abT,
    const int* __restrict__ cnt, const int* __restrict__ elist,
    const float* __restrict__ wlist, float* __restrict__ low, int n)
{
    int e  = blockIdx.x;
    int ks = blockIdx.z;
    int me = cnt[e];

    __align__(16) __shared__ unsigned short hb_s[MT * HS];  // 16.9 KB
    __align__(16) __shared__ unsigned short ab_s[MT * HS];  // 16.9 KB
    __shared__ int   sel_e[MT];
    __shared__ float sel_w[MT];

    int tid  = threadIdx.x;
    int lane = tid & 63, wave = tid >> 6;
    int mhalf = wave >> 1, nhalf = wave & 1;
    int l15 = lane & 15, quad = lane >> 4;

    for (int tile = blockIdx.y; tile * MT < me; tile += gridDim.y) {
        __syncthreads();                   // prev iter readers of sel_* done
        if (tid < MT) {
            int sl = tile * MT + tid;
            int entry = 0; float w = 0.f;
            if (sl < me) {
                entry = elist[(size_t)e * n + sl];
                w     = wlist[(size_t)e * n + sl];
            }
            sel_e[tid] = entry; sel_w[tid] = w;
        }
        __syncthreads();

        f32x4 acc = {0.f, 0.f, 0.f, 0.f};
        for (int c = 0; c < KRANGE / KC; ++c) {     // 2 chunks
            int kbase = ks * KRANGE + c * KC;
            if (c) __syncthreads();                 // prev chunk MFMA reads done
            // stage h rows (gather, fp32->bf16): wave reads one full row/instr
#pragma unroll
            for (int it = 0; it < 8; ++it) {
                int idx = tid + it * 256;
                int row = idx >> 6, c4 = (idx & 63) * 4;
                int tokk = sel_e[row] >> 1;
                float4 v = *(const float4*)&h[(size_t)tokk * DD + kbase + c4];
                ushort4 b;
                b.x = f2bf(v.x); b.y = f2bf(v.y); b.z = f2bf(v.z); b.w = f2bf(v.w);
                *(ushort4*)&hb_s[row * HS + c4] = b;
            }
            // stage abT chunk (already bf16): 32 rows x 512 B, coalesced
#pragma unroll
            for (int it = 0; it < 4; ++it) {
                int idx = tid + it * 256;
                int row = idx >> 5, c8 = (idx & 31) * 8;
                uint4 v = *(const uint4*)&abT[((size_t)e * 32 + row) * DD + kbase + c8];
                *(uint4*)&ab_s[row * HS + c8] = v;
            }
            __syncthreads();
#pragma unroll
            for (int s = 0; s < KC / 32; ++s) {     // 8 MFMA steps
                bf16x8 af = *(const bf16x8*)&hb_s[(mhalf * 16 + l15) * HS + s * 32 + quad * 8];
                bf16x8 bf = *(const bf16x8*)&ab_s[(nhalf * 16 + l15) * HS + s * 32 + quad * 8];
                acc = __builtin_amdgcn_mfma_f32_16x16x32_bf16(af, bf, acc, 0, 0, 0);
            }
        }
        // store: D layout col = lane&15, row = quad*4 + reg  [m89/m91 verified]
#pragma unroll
        for (int r = 0; r < 4; ++r) {
            int mrow = quad * 4 + r;
            int sl = tile * MT + mhalf * 16 + mrow;
            if (sl < me) {
                int   entry = sel_e[mhalf * 16 + mrow];
                float w     = sel_w[mhalf * 16 + mrow];
                low[(size_t)entry * (KS * 32) + ks * 32 + nhalf * 16 + l15] = acc[r] * w;
            }
        }
    }
}

// ---------------- K3: B-side, token-major bucketed, no atomics ---------------
__global__ __launch_bounds__(256) void b_kernel(
    const Route* __restrict__ route, const float* __restrict__ low,
    const float* __restrict__ qb, const float* __restrict__ vb,
    float* __restrict__ outq, float* __restrict__ outv, int n)
{
    int t0 = blockIdx.x * T2;
    int cg = blockIdx.y;               // 0..7 -> q cols, 8..9 -> v cols
    int tid = threadIdx.x;

    __shared__ float acc_s[T2 * 256];  // 32 KB
    __shared__ float ls[T2 * 2 * RR];  // 4 KB
    __shared__ int   elist_s[EE * T2]; // 2 KB
    __shared__ int   ecnt[EE];
    __shared__ int   plist[EE];
    __shared__ int   pcnt;
    __shared__ Route rts[T2];

    if (tid < EE) ecnt[tid] = 0;
    if (tid == 0) pcnt = 0;
    if (tid < T2) {
        int tok = t0 + tid;
        Route rt; rt.i0 = -1; rt.i1 = -1; rt.w0 = 0.f; rt.w1 = 0.f;
        if (tok < n) rt = route[tok];
        rts[tid] = rt;
    }
    __syncthreads();
    if (tid < T2 * 2) {
        int j = tid >> 1, k = tid & 1;
        int e = k ? rts[j].i1 : rts[j].i0;
        if (e >= 0) {
            int p = atomicAdd(&ecnt[e], 1);
            elist_s[e * T2 + p] = j * 2 + k;
        }
    }
    int side = (cg >= CGQ) ? 1 : 0;
    {   // stage ls: 64 slots x 4 float4 == 256 tasks == 1/thread; sum KS partials
        int slot = tid >> 2, r4 = (tid & 3) * 4;
        int j = slot >> 1;
        float4 v = make_float4(0.f, 0.f, 0.f, 0.f);
        if (t0 + j < n) {
            const float* lp = low + (size_t)((t0 + j) * 2 + (slot & 1)) * (KS * 32)
                            + side * 16 + r4;
#pragma unroll
            for (int p = 0; p < KS; ++p) {
                float4 q = *(const float4*)(lp + p * 32);
                v.x += q.x; v.y += q.y; v.z += q.z; v.w += q.w;
            }
        }
        *(float4*)&ls[slot * RR + r4] = v;
    }
#pragma unroll
    for (int j = 0; j < T2; ++j) acc_s[j * 256 + tid] = 0.f;
    __syncthreads();
    if (tid < EE && ecnt[tid] > 0) { int p = atomicAdd(&pcnt, 1); plist[p] = tid; }
    __syncthreads();
    int P = pcnt;

    const float* bp; float* outp; int W, colbase;
    if (cg < CGQ) { bp = qb; outp = outq; W = QO; colbase = cg * 256; }
    else          { bp = vb; outp = outv; W = VO; colbase = (cg - CGQ) * 256; }
    int col = colbase + tid;

    if (P > 0) {
        float bc[RR];
        {
            const float* be = bp + (size_t)plist[0] * RR * W + col;
#pragma unroll
            for (int r = 0; r < RR; ++r) bc[r] = be[(size_t)r * W];
        }
        for (int p = 0; p < P; ++p) {
            float bn[RR];
            if (p + 1 < P) {
                const float* be = bp + (size_t)plist[p + 1] * RR * W + col;
#pragma unroll
                for (int r = 0; r < RR; ++r) bn[r] = be[(size_t)r * W];
            }
            int e = plist[p], c = ecnt[e];
            for (int ii = 0; ii < c; ++ii) {
                int sk = elist_s[e * T2 + ii];
                int j  = sk >> 1;
                const float* lp = &ls[sk * RR];
                float4 l0 = *(const float4*)(lp);
                float4 l1 = *(const float4*)(lp + 4);
                float4 l2 = *(const float4*)(lp + 8);
                float4 l3 = *(const float4*)(lp + 12);
                float v = 0.f;
                v = fmaf(l0.x, bc[0],  v); v = fmaf(l0.y, bc[1],  v);
                v = fmaf(l0.z, bc[2],  v); v = fmaf(l0.w, bc[3],  v);
                v = fmaf(l1.x, bc[4],  v); v = fmaf(l1.y, bc[5],  v);
                v = fmaf(l1.z, bc[6],  v); v = fmaf(l1.w, bc[7],  v);
                v = fmaf(l2.x, bc[8],  v); v = fmaf(l2.y, bc[9],  v);
                v = fmaf(l2.z, bc[10], v); v = fmaf(l2.w, bc[11], v);
                v = fmaf(l3.x, bc[12], v); v = fmaf(l3.y, bc[13], v);
                v = fmaf(l3.z, bc[14], v); v = fmaf(l3.w, bc[15], v);
                acc_s[j * 256 + tid] += v;   // thread-private column
            }
            if (p + 1 < P) {
#pragma unroll
                for (int r = 0; r < RR; ++r) bc[r] = bn[r];
            }
        }
    }
    __syncthreads();
    for (int t = tid; t < T2 * 64; t += 256) {  // row-contiguous float4 stores
        int j = t >> 6, fq = (t & 63) * 4;
        int tok = t0 + j;
        if (tok < n) {
            float4 v = *(const float4*)&acc_s[j * 256 + fq];
            *(float4*)&outp[(size_t)tok * W + colbase + fq] = v;
        }
    }
}

extern "C" void kernel_launch(void* const* d_in, const int* in_sizes, int n_in,
                              void* d_out, int out_size, void* d_ws, size_t ws_size,
                              hipStream_t stream) {
    const float* h  = (const float*)d_in[0];
    const float* rw = (const float*)d_in[1];
    const float* qa = (const float*)d_in[2];
    const float* qb = (const float*)d_in[3];
    const float* va = (const float*)d_in[4];
    const float* vb = (const float*)d_in[5];

    int n = in_sizes[0] / DD;
    float* out  = (float*)d_out;
    float* outq = out;
    float* outv = out + (size_t)n * QO;

    // workspace layout (n=4096: ~6.9 MB total)
    char* w = (char*)d_ws;
    auto align256 = [](size_t x) { return (x + 255) & ~(size_t)255; };
    Route* route = (Route*)w;                       size_t off = align256((size_t)n * sizeof(Route));
    int*   cnt   = (int*)(w + off);                 off = align256(off + EE * sizeof(int));
    int*   elist = (int*)(w + off);                 off = align256(off + (size_t)EE * n * sizeof(int));
    float* wlist = (float*)(w + off);               off = align256(off + (size_t)EE * n * sizeof(float));
    unsigned short* abT = (unsigned short*)(w + off); off = align256(off + (size_t)EE * 32 * DD * sizeof(unsigned short));
    float* low   = (float*)(w + off);               // n * 2 * KS * 32 * 4 B

    // K0: pack+transpose lora-A weights to bf16 [e][32][2048]
    dim3 g0(EE, 4);
    prep_ab_kernel<<<g0, 256, 0, stream>>>(qa, va, abT);

    // zero per-expert counters (ws is poisoned 0xAA each call)
    hipMemsetAsync(cnt, 0, EE * sizeof(int), stream);

    // K1: router + compaction
    router_kernel<<<(n + 3) / 4, 256, 0, stream>>>(h, rw, route, cnt, elist, wlist, n);

    // K2: MFMA A-side
    int ytiles = (2 * n / EE + MT - 1) / MT + 4;    // avg tiles + skew headroom
    dim3 g2(EE, ytiles, KS);
    a_mfma_kernel<<<g2, 256, 0, stream>>>(h, abT, cnt, elist, wlist, low, n);

    // K3: B-side
    dim3 g3((n + T2 - 1) / T2, CGQ + CGV);
    b_kernel<<<g3, 256, 0, stream>>>(route, low, qb, vb, outq, outv, n);
}